// Round 9
// baseline (4344.023 us; speedup 1.0000x reference)
//
#include <hip/hip_runtime.h>
#include <hip/hip_bf16.h>

typedef __attribute__((ext_vector_type(8))) short bf16x8;   // 8 bf16 MFMA A/B frag
typedef __attribute__((ext_vector_type(4))) short bf16x4;   // 4 bf16 (8B)
typedef __attribute__((ext_vector_type(4))) float floatx4;  // MFMA C/D frag / 16B container

#define MFMA_BF16_16x16x32(a, b, c) __builtin_amdgcn_mfma_f32_16x16x32_bf16((a), (b), (c), 0, 0, 0)

#define B_SZ 64
#define T_SZ 512
#define DIN  1024
#define DH   2048
#define DOUT 1024
#define NBLK 64          // persistent grid
#define NTHR 512         // 8 waves/block -> 2 waves/SIMD
#define NW   8
#define KW   (DH / NW)   // 256 K-range per wave
#define COLS 32          // h columns owned per block
#define HELEMS ((size_t)B_SZ * DH)   // bf16 elems per h buffer

// h tile layout: [DH/16 = 128 tiles][64 m][16 k] bf16 (R8, verified: 8
// fully-used lines per A-frag wave-load).
// R9: h loads are sc0-only -> cached in the XCD's L2. The 8 blocks of an
// XCD then share ONE MALL fetch of the 256KB h instead of 8 (16.8 MB/step
// -> ~2-6 MB/step at the MALL). Staleness is handled by the tag protocol:
// acquire-fence (buffer_inv) after the probe confirms h_t at the MALL,
// and inv-on-retry inside ACQUIRE makes any stale-L2 hit self-correcting.

union f4b8 { floatx4 f; bf16x8 b; };
__device__ inline bf16x8 asb(floatx4 f) { f4b8 u; u.f = f; return u.b; }
union b8u4 { bf16x8 b; unsigned d[4]; };

__device__ inline void st_coh64(unsigned long long* p, unsigned long long v) {
  __hip_atomic_store(p, v, __ATOMIC_RELAXED, __HIP_MEMORY_SCOPE_AGENT);
}

// L2-cacheable coherent-enough load for h batches (sc0: cross-CU within XCD).
#define LD128_L2(dst, ptr) \
  asm volatile("global_load_dwordx4 %0, %1, off sc0" : "=v"(dst) : "v"(ptr))
// MALL-direct probe load (bypass L1+L2): sees the coherence point directly.
#define LD32_COH(dst, ptr) \
  asm volatile("global_load_dword %0, %1, off sc0 sc1" : "=v"(dst) : "v"(ptr))
// plain cached load (read-only XH stream), asm so vmcnt accounting is exact
#define LD64_PLAIN(dst, ptr) \
  asm volatile("global_load_dwordx2 %0, %1, off" : "=v"(dst) : "v"(ptr))
// Counted wait + scheduler fence (rule #18: keep reg-only verify/MFMA below).
#define WAIT_VM(n) do { \
  asm volatile("s_waitcnt vmcnt(" n ")" ::: "memory"); \
  __builtin_amdgcn_sched_barrier(0); } while (0)
// L2 invalidate (emits buffer_inv; also a compiler fence so the batch-issue
// asm below cannot be hoisted above it). Call only at vmcnt=0 points.
#define L2_INV() __builtin_amdgcn_fence(__ATOMIC_ACQUIRE, "agent")

// Issue the 8 A-frag loads for k16 = 2g, 2g+1 from per-thread base hb.
#define ISSUE_GROUP(Ab, g, hb) do { \
  const __hip_bfloat16* _p0 = (hb) + (size_t)(g) * 4096; \
  const __hip_bfloat16* _p1 = _p0 + 2048; \
  LD128_L2(Ab[0], _p0); \
  LD128_L2(Ab[1], _p0 + 256); \
  LD128_L2(Ab[2], _p0 + 512); \
  LD128_L2(Ab[3], _p0 + 768); \
  LD128_L2(Ab[4], _p1); \
  LD128_L2(Ab[5], _p1 + 256); \
  LD128_L2(Ab[6], _p1 + 512); \
  LD128_L2(Ab[7], _p1 + 768); \
} while (0)

// Tag verify: sign bits of all 32 dwords must equal mexp (0 or 0x80008000).
__device__ inline unsigned grp_mismatch(const bf16x8* Ab, unsigned mexp) {
  unsigned acc = 0u;
  #pragma unroll
  for (int j = 0; j < 8; ++j) {
    b8u4 u; u.b = Ab[j];
    acc |= (u.d[0] ^ mexp) | (u.d[1] ^ mexp) | (u.d[2] ^ mexp) | (u.d[3] ^ mexp);
  }
  return acc & 0x80008000u;
}
// Backstop retry. MUST inv before re-issue: a stale L2 line would otherwise
// serve the same stale data forever (sc0 path). Each retry = 1 RT, paced.
#define ACQUIRE(Ab, g, mexp, hb) \
  while (!__all(grp_mismatch((Ab), (mexp)) == 0u)) { \
    __builtin_amdgcn_s_sleep(1); \
    L2_INV(); \
    ISSUE_GROUP(Ab, g, hb); WAIT_VM("0"); }

__device__ inline void clean_grp(bf16x8* Ab) {   // strip tag-1 sign bits
  #pragma unroll
  for (int j = 0; j < 8; ++j) {
    b8u4 u; u.b = Ab[j];
    u.d[0] &= 0x7fff7fffu; u.d[1] &= 0x7fff7fffu;
    u.d[2] &= 0x7fff7fffu; u.d[3] &= 0x7fff7fffu;
    Ab[j] = u.b;
  }
}

// 16 MFMAs consuming group g (k16 = 2g, 2g+1).
#define MFMA_GROUP(Ab, g) do { \
  _Pragma("unroll") \
  for (int _i = 0; _i < 4; ++_i) { \
    acc[_i][0] = MFMA_BF16_16x16x32(Ab[_i], asb(wreg[0][2*(g)]), acc[_i][0]); \
    acc[_i][1] = MFMA_BF16_16x16x32(Ab[_i], asb(wreg[1][2*(g)]), acc[_i][1]); \
  } \
  _Pragma("unroll") \
  for (int _i = 0; _i < 4; ++_i) { \
    acc[_i][0] = MFMA_BF16_16x16x32(Ab[4+_i], asb(wreg[0][2*(g)+1]), acc[_i][0]); \
    acc[_i][1] = MFMA_BF16_16x16x32(Ab[4+_i], asb(wreg[1][2*(g)+1]), acc[_i][1]); \
  } \
} while (0)

__device__ inline bf16x8 cvt8(float4 a, float4 b) {
  union { bf16x8 v; __hip_bfloat16 h[8]; } u;
  u.h[0] = __float2bfloat16(a.x); u.h[1] = __float2bfloat16(a.y);
  u.h[2] = __float2bfloat16(a.z); u.h[3] = __float2bfloat16(a.w);
  u.h[4] = __float2bfloat16(b.x); u.h[5] = __float2bfloat16(b.y);
  u.h[6] = __float2bfloat16(b.z); u.h[7] = __float2bfloat16(b.w);
  return u.v;
}

// ---------------------------------------------------------------------------
// fp32 -> bf16 quantize (RNE), 8 elems/thread.
// ---------------------------------------------------------------------------
__global__ __launch_bounds__(256) void f32_to_bf16(
    const float* __restrict__ in, __hip_bfloat16* __restrict__ out, long n)
{
  long i = ((long)blockIdx.x * 256 + threadIdx.x) * 8;
  if (i + 8 <= n) {
    float4 a = *(const float4*)(in + i);
    float4 b = *(const float4*)(in + i + 4);
    *(bf16x8*)(out + i) = cvt8(a, b);
  }
}

// ---------------------------------------------------------------------------
// Kernel 1: XH = X @ Wxh^T + bxh  (fp32 in, bf16 out). 128x128 tile, BK=64.
// (unchanged, known-good)
// ---------------------------------------------------------------------------
__global__ __launch_bounds__(256) void xh_gemm(
    const float* __restrict__ X,
    const float* __restrict__ W,
    const float* __restrict__ bias,
    __hip_bfloat16* __restrict__ XH)
{
  const int K = DIN;
  const int N = DH;
  __shared__ __hip_bfloat16 As[128][64];
  __shared__ __hip_bfloat16 Bs[128][64];

  const int nb  = N / 128;
  const int bm  = blockIdx.x / nb;
  const int bn  = blockIdx.x % nb;
  const int m0  = bm * 128, n0 = bn * 128;
  const int tid = threadIdx.x;
  const int lane = tid & 63;
  const int wave = tid >> 6;
  const int wm  = (wave >> 1) * 64;
  const int wn  = (wave & 1) * 64;
  const int col = lane & 15;
  const int quad = lane >> 4;

  const floatx4 Z = {0.f, 0.f, 0.f, 0.f};
  floatx4 acc[4][4];
  #pragma unroll
  for (int i = 0; i < 4; ++i)
    #pragma unroll
    for (int j = 0; j < 4; ++j) acc[i][j] = Z;

  const int srow = tid >> 3;
  const int scol = (tid & 7) * 8;

  for (int k0 = 0; k0 < K; k0 += 64) {
    __syncthreads();
    #pragma unroll
    for (int p = 0; p < 4; ++p) {
      int r = srow + p * 32;
      const float* xs = &X[(long)(m0 + r) * K + k0 + scol];
      const float* wsrc = &W[(long)(n0 + r) * K + k0 + scol];
      *(bf16x8*)(&As[r][scol]) = cvt8(*(const float4*)xs,   *(const float4*)(xs + 4));
      *(bf16x8*)(&Bs[r][scol]) = cvt8(*(const float4*)wsrc, *(const float4*)(wsrc + 4));
    }
    __syncthreads();
    #pragma unroll
    for (int kk = 0; kk < 64; kk += 32) {
      const int kr = kk + quad * 8;
      bf16x8 a[4], b[4];
      #pragma unroll
      for (int i = 0; i < 4; ++i) a[i] = *(const bf16x8*)(&As[wm + i*16 + col][kr]);
      #pragma unroll
      for (int j = 0; j < 4; ++j) b[j] = *(const bf16x8*)(&Bs[wn + j*16 + col][kr]);
      #pragma unroll
      for (int i = 0; i < 4; ++i)
        #pragma unroll
        for (int j = 0; j < 4; ++j)
          acc[i][j] = MFMA_BF16_16x16x32(a[i], b[j], acc[i][j]);
    }
  }

  #pragma unroll
  for (int j = 0; j < 4; ++j) {
    const int n = n0 + wn + j*16 + col;
    const float bv = bias[n];
    #pragma unroll
    for (int i = 0; i < 4; ++i) {
      const int mr = m0 + wm + i*16 + quad*4;
      #pragma unroll
      for (int r = 0; r < 4; ++r)
        XH[(long)(mr + r) * N + n] = __float2bfloat16(acc[i][j][r] + bv);
    }
  }
}

// ---------------------------------------------------------------------------
// Kernel 2: persistent Elman recurrence + final projection.
//   R8 structure (tile layout, tag dataflow, probe, counted 2-buffer
//   pipeline, 2 intra-block barriers, 64 in-flight A-regs) + R9 change:
//   h batch loads are sc0-only (L2-cached per XCD) with a per-step
//   buffer_inv (acquire fence) AFTER the MALL-direct probe passes and
//   BEFORE the batch issues. Tag-verify + inv-on-retry makes all inv
//   timing races (and cross-launch stale L2 lines) self-correcting.
// ---------------------------------------------------------------------------
__global__ __launch_bounds__(NTHR, 2) void elman_persistent(
    const __hip_bfloat16* __restrict__ XH,    // [64][512][2048] bf16
    const __hip_bfloat16* __restrict__ Whh,   // [2048][2048] bf16
    const __hip_bfloat16* __restrict__ Why,   // [1024][2048] bf16
    const float* __restrict__ bhy,            // [1024] fp32
    __hip_bfloat16* __restrict__ hbuf,        // [2][128][64][16] bf16 (buf0=0x00, buf1=0x80)
    float* __restrict__ Y)                    // [64][1024] fp32 = d_out
{
  __shared__ __align__(16) float partial[NW][B_SZ][COLS + 4];  // [8][64][36]
  const int tid  = threadIdx.x;
  const int lane = tid & 63;
  const int wave = tid >> 6;        // 0..7
  const int bid  = blockIdx.x;
  const int n0   = bid * COLS;
  const int col  = lane & 15;
  const int quad = lane >> 4;
  const int kw   = wave * KW;       // this wave's K base

  const int mrow = tid >> 3;        // reduce/store: batch row (0..63)
  const int grp  = tid & 7;         // 8 col-groups of 4
  const int mcol = grp * 4;

  // Probe: first dword of producer (8*wave + lane&7)'s tile range.
  const size_t pelem = (size_t)(8 * wave + (lane & 7)) * 2048;

  // h-store address (tile layout): 8B store of 4 contiguous k at row mrow.
  const size_t soff = (size_t)((n0 + mcol) >> 4) * 1024 + (size_t)mrow * 16
                    + (size_t)((n0 + mcol) & 15);

  // Per-thread A-frag read base within a buffer.
  const size_t roff = (size_t)((kw >> 4) + (quad >> 1)) * 1024
                    + (size_t)col * 16 + (size_t)(quad & 1) * 8;

  // Pin Whh B-frags (asm anti-remat). 2 n-frags x 8 k16 x 16B = 64 VGPR.
  floatx4 wreg[2][8];
  #pragma unroll
  for (int nf = 0; nf < 2; ++nf) {
    const __hip_bfloat16* wrow = Whh + (long)(n0 + nf*16 + col) * DH + kw + quad * 8;
    #pragma unroll
    for (int k16 = 0; k16 < 8; ++k16) {
      wreg[nf][k16] = *(const floatx4*)(wrow + k16 * 32);
      asm volatile("" : "+v"(wreg[nf][k16]));
    }
  }

  const __hip_bfloat16* xptr = XH + (size_t)mrow * T_SZ * DH + n0 + mcol;

  // Prologue: probe h_0 (buf0, trivially fresh) + xh_0 prefetch.
  unsigned pv;
  bf16x4 xv, xvn;
  LD32_COH(pv, (const unsigned*)(hbuf + pelem));
  LD64_PLAIN(xvn, xptr);

  const floatx4 Z = {0.f, 0.f, 0.f, 0.f};

  for (int t = 0; t < T_SZ; ++t) {
    const unsigned mexp = ((t >> 1) & 1) ? 0x80008000u : 0u;           // tag of h_t
    const unsigned long long smask =
        (((t + 1) >> 1) & 1) ? 0x8000800080008000ull : 0ull;           // tag of h_{t+1}

    // Tail-issued ops (h-store, probe, xh) retire here; RTs overlapped bar 2.
    WAIT_VM("0");
    xv = xvn;

    const __hip_bfloat16* hb = hbuf + (size_t)(t & 1) * HELEMS + roff;
    const unsigned* pp = (const unsigned*)(hbuf + (size_t)(t & 1) * HELEMS + pelem);

    // Freshness spin on the MALL-direct probe (1 dword RT per re-poll).
    while (!__all(((pv ^ mexp) & 0x80008000u) == 0u)) {
      __builtin_amdgcn_s_sleep(1);
      LD32_COH(pv, pp);
      WAIT_VM("0");
    }

    // h_t is at the MALL: drop stale L2 lines, then fetch via L2 (sc0).
    // 8 blocks/XCD share the L2 fill -> ~8x less MALL traffic than sc1.
    L2_INV();

    // Counted 2-buffer pipeline (R5-verified): 64 A-regs in flight max.
    floatx4 acc[4][2];
    #pragma unroll
    for (int i = 0; i < 4; ++i) { acc[i][0] = Z; acc[i][1] = Z; }

    bf16x8 A0[8], A1[8];
    ISSUE_GROUP(A0, 0, hb);
    ISSUE_GROUP(A1, 1, hb);
    WAIT_VM("8");
    ACQUIRE(A0, 0, mexp, hb);
    if (mexp) clean_grp(A0);
    MFMA_GROUP(A0, 0);
    ISSUE_GROUP(A0, 2, hb);
    WAIT_VM("8");
    ACQUIRE(A1, 1, mexp, hb);
    if (mexp) clean_grp(A1);
    MFMA_GROUP(A1, 1);
    ISSUE_GROUP(A1, 3, hb);
    WAIT_VM("8");
    ACQUIRE(A0, 2, mexp, hb);
    if (mexp) clean_grp(A0);
    MFMA_GROUP(A0, 2);
    WAIT_VM("0");
    ACQUIRE(A1, 3, mexp, hb);
    if (mexp) clean_grp(A1);
    MFMA_GROUP(A1, 3);

    // partials to LDS (C/D: m = i*16+quad*4+r, n = nf*16+col)
    #pragma unroll
    for (int i = 0; i < 4; ++i)
      #pragma unroll
      for (int nf = 0; nf < 2; ++nf)
        #pragma unroll
        for (int r = 0; r < 4; ++r)
          partial[wave][i*16 + quad*4 + r][nf*16 + col] = acc[i][nf][r];
    __syncthreads();   // barrier 1: partial writes -> reduce reads (vmcnt=0 here)

    // reduce 8 waves, + xh_t, relu, tag signs, write-through u64 store
    {
      floatx4 s = Z;
      #pragma unroll
      for (int w = 0; w < NW; ++w)
        s += *(const floatx4*)(&partial[w][mrow][mcol]);
      union { bf16x4 v; __hip_bfloat16 hh[4]; unsigned long long q; } o, xu;
      xu.v = xv;
      #pragma unroll
      for (int c = 0; c < 4; ++c) {
        float v = s[c] + __bfloat162float(xu.hh[c]);
        v = v > 0.f ? v : 0.f;
        o.hh[c] = __float2bfloat16(v);
      }
      o.q |= smask;   // stamp step tag into sign bits (values >= 0)
      st_coh64((unsigned long long*)(hbuf + (size_t)((t + 1) & 1) * HELEMS + soff),
               o.q);
    }

    // Tail: next step's probe + xh prefetch ride across barrier 2 with the
    // h-store ack.
    LD32_COH(pv, (const unsigned*)(hbuf + (size_t)((t + 1) & 1) * HELEMS + pelem));
    {
      const int xi = (t + 1 < T_SZ) ? t + 1 : T_SZ - 1;
      LD64_PLAIN(xvn, xptr + (size_t)xi * DH);
    }

    // barrier 2 (raw, NO vmcnt drain): step-t reduce reads complete before
    // any wave's step-t+1 partial writes; store+probe+xh stay in flight.
    asm volatile("s_waitcnt lgkmcnt(0)" ::: "memory");
    __builtin_amdgcn_s_barrier();
    __builtin_amdgcn_sched_barrier(0);
  }

  // Final projection: y = h_final @ Why^T + bhy  (blocks 0..31, fp32 out).
  // h_512 is in buf0, tag (512>>1)&1 = 0. Probe for it was issued at t=511.
  if (n0 < DOUT) {
    WAIT_VM("0");
    const unsigned* pp = (const unsigned*)(hbuf + pelem);
    while (!__all((pv & 0x80008000u) == 0u)) {
      __builtin_amdgcn_s_sleep(1);
      LD32_COH(pv, pp);
      WAIT_VM("0");
    }
    L2_INV();
    const __hip_bfloat16* hb = hbuf + roff;   // buf0
    floatx4 acc[4][2];
    #pragma unroll
    for (int i = 0; i < 4; ++i) { acc[i][0] = Z; acc[i][1] = Z; }
    bf16x8 A0[8];
    #pragma unroll
    for (int g = 0; g < 4; ++g) {
      ISSUE_GROUP(A0, g, hb);
      WAIT_VM("0");
      ACQUIRE(A0, g, 0u, hb);
      #pragma unroll
      for (int kk = 0; kk < 2; ++kk) {
        const int k16 = 2*g + kk;
        bf16x8 b0 = *(const bf16x8*)(Why + (long)(n0 +      col) * DH + kw + k16*32 + quad*8);
        bf16x8 b1 = *(const bf16x8*)(Why + (long)(n0 + 16 + col) * DH + kw + k16*32 + quad*8);
        #pragma unroll
        for (int i = 0; i < 4; ++i) {
          acc[i][0] = MFMA_BF16_16x16x32(A0[4*kk + i], b0, acc[i][0]);
          acc[i][1] = MFMA_BF16_16x16x32(A0[4*kk + i], b1, acc[i][1]);
        }
      }
    }
    #pragma unroll
    for (int i = 0; i < 4; ++i)
      #pragma unroll
      for (int nf = 0; nf < 2; ++nf)
        #pragma unroll
        for (int r = 0; r < 4; ++r)
          partial[wave][i*16 + quad*4 + r][nf*16 + col] = acc[i][nf][r];
    __syncthreads();
    {
      floatx4 s = Z;
      #pragma unroll
      for (int w = 0; w < NW; ++w)
        s += *(const floatx4*)(&partial[w][mrow][mcol]);
      float4 bv = *(const float4*)(&bhy[n0 + mcol]);
      float4 out;
      out.x = s[0] + bv.x; out.y = s[1] + bv.y;
      out.z = s[2] + bv.z; out.w = s[3] + bv.w;
      *(float4*)(&Y[(size_t)mrow * DOUT + n0 + mcol]) = out;
    }
  }
}

// ---------------------------------------------------------------------------
extern "C" void kernel_launch(void* const* d_in, const int* in_sizes, int n_in,
                              void* d_out, int out_size, void* d_ws, size_t ws_size,
                              hipStream_t stream) {
  const float* x   = (const float*)d_in[0];
  const float* Wxh = (const float*)d_in[1];
  const float* bxh = (const float*)d_in[2];
  const float* Whh = (const float*)d_in[3];
  const float* Why = (const float*)d_in[4];
  const float* bhy = (const float*)d_in[5];
  float* y = (float*)d_out;

  char* ws = (char*)d_ws;
  const size_t XH_BYTES  = (size_t)B_SZ * T_SZ * DH * 2;   // 128 MiB
  const size_t WHH_BYTES = (size_t)DH * DH * 2;            // 8 MiB
  const size_t WHY_BYTES = (size_t)DOUT * DH * 2;          // 4 MiB
  const size_t HB        = (size_t)HELEMS * 2;             // 256 KiB per buffer
  __hip_bfloat16* XH     = (__hip_bfloat16*)ws;
  __hip_bfloat16* Whh_bf = (__hip_bfloat16*)(ws + XH_BYTES);
  __hip_bfloat16* Why_bf = (__hip_bfloat16*)(ws + XH_BYTES + WHH_BYTES);
  __hip_bfloat16* hbuf   = (__hip_bfloat16*)(ws + XH_BYTES + WHH_BYTES + WHY_BYTES);

  hipMemsetAsync(hbuf, 0x00, HB, stream);                  // buf0 = h_0 = +0, tag 0
  hipMemsetAsync((char*)hbuf + HB, 0x80, HB, stream);      // buf1 = stale-tag pattern
  f32_to_bf16<<<dim3((DH*DH)/(256*8)),   dim3(256), 0, stream>>>(Whh, Whh_bf, (long)DH*DH);
  f32_to_bf16<<<dim3((DOUT*DH)/(256*8)), dim3(256), 0, stream>>>(Why, Why_bf, (long)DOUT*DH);
  xh_gemm<<<dim3((32768/128) * (DH/128)), dim3(256), 0, stream>>>(x, Wxh, bxh, XH);
  elman_persistent<<<dim3(NBLK), dim3(NTHR), 0, stream>>>(
      XH, Whh_bf, Why_bf, bhy, hbuf, y);
}